// Round 6
// baseline (1338.240 us; speedup 1.0000x reference)
//
#include <hip/hip_runtime.h>
#include <hip/hip_fp16.h>

#define FD 128          // feature dim
#define RPB 4           // rows (waves) per block; block = 256 threads
// NOTE: algebraic elimination of b_{M-1} assumes M >= 4 (here M = 30).
// Monolithic fp16 recurrence state (error-critical -b_{k+2} path) + fp8 e4m3
// MIRROR planes [N][128B] used ONLY as the gather source. fp8 error enters
// only through 2*L@(.) which contracts by ~0.14; the fp16 feedthrough path is
// untouched. Gather volume halves (204.8 -> 102.4 MB/step) and the gathered
// footprint halves (12.8 -> 6.4 MB -> ~2x L2 hit rate). Gather instruction
// geometry preserved: uint4/lane, 8 edges x 128B = 1KB = 8 full lines/instr.

// ---------------- CSR build ----------------

__global__ void zero_i32(int* __restrict__ p, int n) {
  int i = blockIdx.x * blockDim.x + threadIdx.x;
  if (i < n) p[i] = 0;
}

__global__ void hist_kernel(const int* __restrict__ rows, int* __restrict__ cnt, int nnz) {
  int i = blockIdx.x * blockDim.x + threadIdx.x;
  if (i < nnz) atomicAdd(&cnt[rows[i]], 1);
}

// coalesced 3-phase scan
__global__ void block_reduce(const int* __restrict__ cnt, int* __restrict__ bsum, int n) {
  __shared__ int sm[256];
  int i = blockIdx.x * 256 + threadIdx.x;
  sm[threadIdx.x] = (i < n) ? cnt[i] : 0;
  __syncthreads();
  for (int off = 128; off > 0; off >>= 1) {
    if (threadIdx.x < off) sm[threadIdx.x] += sm[threadIdx.x + off];
    __syncthreads();
  }
  if (threadIdx.x == 0) bsum[blockIdx.x] = sm[0];
}

__global__ void scan_bsum(const int* __restrict__ bsum, int* __restrict__ bpre, int nb) {
  __shared__ int sm[1024];
  const int tid = threadIdx.x;
  sm[tid] = (tid < nb) ? bsum[tid] : 0;
  __syncthreads();
  for (int off = 1; off < 1024; off <<= 1) {
    int t = (tid >= off) ? sm[tid - off] : 0;
    __syncthreads();
    sm[tid] += t;
    __syncthreads();
  }
  if (tid < nb) bpre[tid] = (tid == 0) ? 0 : sm[tid - 1];
}

__global__ void block_scan(const int* __restrict__ cnt, const int* __restrict__ bpre,
                           int* __restrict__ row_ptr, int n) {
  __shared__ int sm[256];
  const int tid = threadIdx.x;
  int i = blockIdx.x * 256 + tid;
  sm[tid] = (i < n) ? cnt[i] : 0;
  __syncthreads();
  for (int off = 1; off < 256; off <<= 1) {
    int t = (tid >= off) ? sm[tid - off] : 0;
    __syncthreads();
    sm[tid] += t;
    __syncthreads();
  }
  if (i < n) row_ptr[i + 1] = sm[tid] + bpre[blockIdx.x];
  if (i == 0) row_ptr[0] = 0;
}

__global__ void copy_i32(const int* __restrict__ src, int* __restrict__ dst, int n) {
  int i = blockIdx.x * blockDim.x + threadIdx.x;
  if (i < n) dst[i] = src[i];
}

// packed edge scatter: one 8B store per edge. Column stored PRE-SCALED to the
// fp8-plane byte offset (col * 128 = col << 7) so the gather address is one add.
__global__ void scatter_kernel(const int* __restrict__ rows, const int* __restrict__ cols,
                               const float* __restrict__ vals, int* __restrict__ fill,
                               int2* __restrict__ pk, int nnz) {
  int i = blockIdx.x * blockDim.x + threadIdx.x;
  if (i < nnz) {
    int r = rows[i];
    int pos = atomicAdd(&fill[r], 1);
    pk[pos] = make_int2(cols[i] << 7, __float_as_int(vals[i]));
  }
}

// f32 [N][128] -> fp16 Xh [N][128] + fp8 X8 mirror (uint = 4 fp8 per thread-item)
__global__ void f32_to_f16_f8(const float* __restrict__ src, __half* __restrict__ dst,
                              unsigned int* __restrict__ dst8, int n4) {
  int i = blockIdx.x * blockDim.x + threadIdx.x;
  if (i < n4) {
    float4 v = ((const float4*)src)[i];
    __half2* d = (__half2*)dst + 2 * (size_t)i;
    d[0] = __floats2half2_rn(v.x, v.y);
    d[1] = __floats2half2_rn(v.z, v.w);
    int w = 0;
    w = __builtin_amdgcn_cvt_pk_fp8_f32(v.x, v.y, w, false);
    w = __builtin_amdgcn_cvt_pk_fp8_f32(v.z, v.w, w, true);
    dst8[i] = (unsigned int)w;
  }
}

// ---------------- fp8 wide gather ----------------
// Wave = 1 row. sub = lane>>3 picks 1 of 8 edges; fl = lane&7 picks a uint4
// (16 fp8 = 16 features). One gather instruction covers 8 edges x 128B = 1KB
// over 8 fully-used lines (round-0-proven geometry). Tfl = base + fl*16;
// cb is a pre-scaled byte offset. Each lane accumulates 16 features.

typedef float v2f __attribute__((ext_vector_type(2)));

__device__ __forceinline__ void fma_edge8(const char* __restrict__ Tfl, int cb, float v,
                                          float acc[16]) {
  uint4 raw = *(const uint4*)(Tfl + cb);
  v2f f;
  f = __builtin_amdgcn_cvt_pk_f32_fp8((int)raw.x, false);
  acc[0] = fmaf(v, f.x, acc[0]);  acc[1] = fmaf(v, f.y, acc[1]);
  f = __builtin_amdgcn_cvt_pk_f32_fp8((int)raw.x, true);
  acc[2] = fmaf(v, f.x, acc[2]);  acc[3] = fmaf(v, f.y, acc[3]);
  f = __builtin_amdgcn_cvt_pk_f32_fp8((int)raw.y, false);
  acc[4] = fmaf(v, f.x, acc[4]);  acc[5] = fmaf(v, f.y, acc[5]);
  f = __builtin_amdgcn_cvt_pk_f32_fp8((int)raw.y, true);
  acc[6] = fmaf(v, f.x, acc[6]);  acc[7] = fmaf(v, f.y, acc[7]);
  f = __builtin_amdgcn_cvt_pk_f32_fp8((int)raw.z, false);
  acc[8] = fmaf(v, f.x, acc[8]);  acc[9] = fmaf(v, f.y, acc[9]);
  f = __builtin_amdgcn_cvt_pk_f32_fp8((int)raw.z, true);
  acc[10] = fmaf(v, f.x, acc[10]); acc[11] = fmaf(v, f.y, acc[11]);
  f = __builtin_amdgcn_cvt_pk_f32_fp8((int)raw.w, false);
  acc[12] = fmaf(v, f.x, acc[12]); acc[13] = fmaf(v, f.y, acc[13]);
  f = __builtin_amdgcn_cvt_pk_f32_fp8((int)raw.w, true);
  acc[14] = fmaf(v, f.x, acc[14]); acc[15] = fmaf(v, f.y, acc[15]);
}

__device__ __forceinline__ void gather_row(const int* __restrict__ rp,
                                           const int2* __restrict__ pk,
                                           const char* __restrict__ Tfl,
                                           int r, int sub, float acc[16]) {
  int e = rp[r];
  const int end = rp[r + 1];
  for (; e + 16 <= end; e += 16) {
    int2 cv0 = pk[e + sub];
    int2 cv1 = pk[e + 8 + sub];
    fma_edge8(Tfl, cv0.x, __int_as_float(cv0.y), acc);
    fma_edge8(Tfl, cv1.x, __int_as_float(cv1.y), acc);
  }
  if (e + 8 <= end) {
    int2 cv = pk[e + sub];
    fma_edge8(Tfl, cv.x, __int_as_float(cv.y), acc);
    e += 8;
  }
  if (e < end) {
    int idx = e + sub;
    int2 cv = pk[min(idx, end - 1)];
    float v = (idx < end) ? __int_as_float(cv.y) : 0.f;
    fma_edge8(Tfl, cv.x, v, acc);
  }
}

__device__ __forceinline__ void reduce_subs(float acc[16]) {
#pragma unroll
  for (int m = 8; m < 64; m <<= 1) {
#pragma unroll
    for (int j = 0; j < 16; ++j) acc[j] += __shfl_xor(acc[j], m, 64);
  }
}

// ---------------- Clenshaw steps ----------------
// b_k = g2*(L @ src8) - p + ck_eff * X   (fp16 state + fp8 gather mirror, fp32 math)
// flags: bit0 = read p from pd; bit1 = ck_eff = c_k - c_{M-1} (folds b_{M-1});
//        bit2 = g2 = 2*c_{M-1} (src8 is X8 standing in for b_{M-1} = c_{M-1} X).
// pd holds b_{k+2} (fp16) and receives b_k in place; dst8 receives the fp8 mirror.
// Epilogue rows (Xh, pd) load BEFORE the gather so their latency hides under it.

__global__ __launch_bounds__(256) void clen_step(
    const int* __restrict__ rp, const int2* __restrict__ pk,
    const unsigned char* __restrict__ src8, const __half* __restrict__ Xh, __half* pd,
    unsigned char* __restrict__ dst8,
    const float* __restrict__ coeffs, int k, int flags, int M, int n) {
  const int lane = threadIdx.x & 63;
  const int sub = lane >> 3, fl = lane & 7;
  const int r = blockIdx.x * RPB + (threadIdx.x >> 6);
  if (r >= n) return;
  const char* Tfl = (const char*)src8 + fl * 16;

  uint4 xr0 = make_uint4(0,0,0,0), xr1 = make_uint4(0,0,0,0);
  uint4 pr0 = make_uint4(0,0,0,0), pr1 = make_uint4(0,0,0,0);
  if (sub == 0) {
    xr0 = ((const uint4*)(Xh + (size_t)r * FD))[fl * 2];
    xr1 = ((const uint4*)(Xh + (size_t)r * FD))[fl * 2 + 1];
    if (flags & 1) {
      pr0 = ((const uint4*)(pd + (size_t)r * FD))[fl * 2];
      pr1 = ((const uint4*)(pd + (size_t)r * FD))[fl * 2 + 1];
    }
  }

  float acc[16];
#pragma unroll
  for (int j = 0; j < 16; ++j) acc[j] = 0.f;
  gather_row(rp, pk, Tfl, r, sub, acc);
  reduce_subs(acc);

  if (sub == 0) {
    float ck = coeffs[k];
    if (flags & 2) ck -= coeffs[M - 1];
    const float g2 = (flags & 4) ? 2.f * coeffs[M - 1] : 2.f;
    const __half2* xh0 = (const __half2*)&xr0;
    const __half2* xh1 = (const __half2*)&xr1;
    const __half2* ph0 = (const __half2*)&pr0;
    const __half2* ph1 = (const __half2*)&pr1;
    float t[16];
#pragma unroll
    for (int q = 0; q < 4; ++q) {
      float2 x = __half22float2(xh0[q]);
      float2 p = (flags & 1) ? __half22float2(ph0[q]) : make_float2(0.f, 0.f);
      t[2*q]   = fmaf(g2, acc[2*q],   fmaf(ck, x.x, -p.x));
      t[2*q+1] = fmaf(g2, acc[2*q+1], fmaf(ck, x.y, -p.y));
    }
#pragma unroll
    for (int q = 0; q < 4; ++q) {
      float2 x = __half22float2(xh1[q]);
      float2 p = (flags & 1) ? __half22float2(ph1[q]) : make_float2(0.f, 0.f);
      t[8+2*q]   = fmaf(g2, acc[8+2*q],   fmaf(ck, x.x, -p.x));
      t[8+2*q+1] = fmaf(g2, acc[8+2*q+1], fmaf(ck, x.y, -p.y));
    }
    uint4 o0, o1;
    __half2* oh0 = (__half2*)&o0;
    __half2* oh1 = (__half2*)&o1;
#pragma unroll
    for (int q = 0; q < 4; ++q) {
      oh0[q] = __floats2half2_rn(t[2*q], t[2*q+1]);
      oh1[q] = __floats2half2_rn(t[8+2*q], t[8+2*q+1]);
    }
    ((uint4*)(pd + (size_t)r * FD))[fl * 2] = o0;
    ((uint4*)(pd + (size_t)r * FD))[fl * 2 + 1] = o1;
    // fp8 mirror: 16 features -> uint4
    uint4 m8;
    int w;
    w = 0;
    w = __builtin_amdgcn_cvt_pk_fp8_f32(t[0], t[1], w, false);
    w = __builtin_amdgcn_cvt_pk_fp8_f32(t[2], t[3], w, true);
    m8.x = (unsigned int)w;
    w = 0;
    w = __builtin_amdgcn_cvt_pk_fp8_f32(t[4], t[5], w, false);
    w = __builtin_amdgcn_cvt_pk_fp8_f32(t[6], t[7], w, true);
    m8.y = (unsigned int)w;
    w = 0;
    w = __builtin_amdgcn_cvt_pk_fp8_f32(t[8], t[9], w, false);
    w = __builtin_amdgcn_cvt_pk_fp8_f32(t[10], t[11], w, true);
    m8.z = (unsigned int)w;
    w = 0;
    w = __builtin_amdgcn_cvt_pk_fp8_f32(t[12], t[13], w, false);
    w = __builtin_amdgcn_cvt_pk_fp8_f32(t[14], t[15], w, true);
    m8.w = (unsigned int)w;
    ((uint4*)(dst8 + (size_t)r * FD))[fl] = m8;
  }
}

// out = c0*X + L @ b1 - b2   (fp32 X and output; b1 gathered from fp8 mirror)
__global__ __launch_bounds__(256) void clen_final(
    const int* __restrict__ rp, const int2* __restrict__ pk,
    const unsigned char* __restrict__ b18, const __half* __restrict__ b2,
    const float* __restrict__ X, float* __restrict__ out,
    const float* __restrict__ coeffs, int n) {
  const int lane = threadIdx.x & 63;
  const int sub = lane >> 3, fl = lane & 7;
  const int r = blockIdx.x * RPB + (threadIdx.x >> 6);
  if (r >= n) return;
  const char* Tfl = (const char*)b18 + fl * 16;

  uint4 pr0 = make_uint4(0,0,0,0), pr1 = make_uint4(0,0,0,0);
  float4 x0 = make_float4(0.f,0.f,0.f,0.f), x1 = make_float4(0.f,0.f,0.f,0.f);
  float4 x2 = make_float4(0.f,0.f,0.f,0.f), x3 = make_float4(0.f,0.f,0.f,0.f);
  if (sub == 0) {
    pr0 = ((const uint4*)(b2 + (size_t)r * FD))[fl * 2];
    pr1 = ((const uint4*)(b2 + (size_t)r * FD))[fl * 2 + 1];
    const float4* Xr = (const float4*)(X + (size_t)r * FD);
    x0 = Xr[fl * 4]; x1 = Xr[fl * 4 + 1]; x2 = Xr[fl * 4 + 2]; x3 = Xr[fl * 4 + 3];
  }

  float acc[16];
#pragma unroll
  for (int j = 0; j < 16; ++j) acc[j] = 0.f;
  gather_row(rp, pk, Tfl, r, sub, acc);
  reduce_subs(acc);

  if (sub == 0) {
    const float c0 = coeffs[0];
    const __half2* ph0 = (const __half2*)&pr0;
    const __half2* ph1 = (const __half2*)&pr1;
    float p[16];
#pragma unroll
    for (int q = 0; q < 4; ++q) {
      float2 a = __half22float2(ph0[q]);
      p[2*q] = a.x; p[2*q+1] = a.y;
      float2 b = __half22float2(ph1[q]);
      p[8+2*q] = b.x; p[8+2*q+1] = b.y;
    }
    float4 o0, o1, o2, o3;
    o0.x = fmaf(c0, x0.x, acc[0] - p[0]);
    o0.y = fmaf(c0, x0.y, acc[1] - p[1]);
    o0.z = fmaf(c0, x0.z, acc[2] - p[2]);
    o0.w = fmaf(c0, x0.w, acc[3] - p[3]);
    o1.x = fmaf(c0, x1.x, acc[4] - p[4]);
    o1.y = fmaf(c0, x1.y, acc[5] - p[5]);
    o1.z = fmaf(c0, x1.z, acc[6] - p[6]);
    o1.w = fmaf(c0, x1.w, acc[7] - p[7]);
    o2.x = fmaf(c0, x2.x, acc[8] - p[8]);
    o2.y = fmaf(c0, x2.y, acc[9] - p[9]);
    o2.z = fmaf(c0, x2.z, acc[10] - p[10]);
    o2.w = fmaf(c0, x2.w, acc[11] - p[11]);
    o3.x = fmaf(c0, x3.x, acc[12] - p[12]);
    o3.y = fmaf(c0, x3.y, acc[13] - p[13]);
    o3.z = fmaf(c0, x3.z, acc[14] - p[14]);
    o3.w = fmaf(c0, x3.w, acc[15] - p[15]);
    float4* Or = (float4*)(out + (size_t)r * FD);
    Or[fl * 4] = o0; Or[fl * 4 + 1] = o1; Or[fl * 4 + 2] = o2; Or[fl * 4 + 3] = o3;
  }
}

// ---------------- launch ----------------

extern "C" void kernel_launch(void* const* d_in, const int* in_sizes, int n_in,
                              void* d_out, int out_size, void* d_ws, size_t ws_size,
                              hipStream_t stream) {
  const int* rows = (const int*)d_in[0];
  const int* cols = (const int*)d_in[1];
  const float* vals = (const float*)d_in[2];
  const float* X = (const float*)d_in[3];
  const float* coeffs = (const float*)d_in[4];
  float* out = (float*)d_out;

  const int nnz = in_sizes[0];
  const int n = in_sizes[3] / FD;
  const int M = in_sizes[4];

  auto align_up = [](size_t x) { return (x + 255) & ~(size_t)255; };
  char* w = (char*)d_ws;
  size_t off = 0;
  int* row_ptr = (int*)(w + off); off = align_up(off + (size_t)(n + 1) * 4);
  int* row_fill = (int*)(w + off); off = align_up(off + (size_t)n * 4);
  int* bsum = (int*)(w + off); off = align_up(off + 1024 * 4);
  int* bpre = (int*)(w + off); off = align_up(off + 1024 * 4);
  int2* pk = (int2*)(w + off); off = align_up(off + (size_t)nnz * 8);
  __half* Xh = (__half*)(w + off); off = align_up(off + (size_t)n * FD * 2);
  __half* buf0 = (__half*)(w + off); off = align_up(off + (size_t)n * FD * 2);
  __half* buf1 = (__half*)(w + off); off = align_up(off + (size_t)n * FD * 2);
  unsigned char* m80 = (unsigned char*)(w + off); off = align_up(off + (size_t)n * FD);
  unsigned char* m81 = (unsigned char*)(w + off); off = align_up(off + (size_t)n * FD);
  __half* bufs[2] = {buf0, buf1};
  unsigned char* m8[2] = {m80, m81};
  (void)ws_size;

  const int B = 256;
  const int gN = (n + B - 1) / B;
  const int gE = (nnz + B - 1) / B;
  const int gS = (n + RPB - 1) / RPB;
  const int n4 = n * FD / 4;
  const int gC = (n4 + B - 1) / B;

  // CSR build
  zero_i32<<<gN, B, 0, stream>>>(row_fill, n);
  hist_kernel<<<gE, B, 0, stream>>>(rows, row_fill, nnz);
  block_reduce<<<gN, B, 0, stream>>>(row_fill, bsum, n);
  scan_bsum<<<1, 1024, 0, stream>>>(bsum, bpre, gN);
  block_scan<<<gN, B, 0, stream>>>(row_fill, bpre, row_ptr, n);
  copy_i32<<<gN, B, 0, stream>>>(row_ptr, row_fill, n);
  scatter_kernel<<<gE, B, 0, stream>>>(rows, cols, vals, row_fill, pk, nnz);
  // X -> fp16 Xh + fp8 X8; X8 lives in m8[(M-1)&1] (the plane step M-2 gathers,
  // and which is first overwritten only at step M-3, after X8 is done serving).
  f32_to_f16_f8<<<gC, B, 0, stream>>>(X, Xh, (unsigned int*)m8[(M - 1) & 1], n4);

  // Clenshaw (b_{M-1} = c_{M-1} X eliminated algebraically; M >= 4):
  // k = M-2: b = 2 c_{M-1} (L X8) + c_{M-2} X            [flags = 4]
  // k = M-3: b = 2 (L b8_{M-2}) + (c_{M-3} - c_{M-1}) X  [flags = 2]
  // k = M-4..1: b = 2 (L b8_{k+1}) - b_{k+2} + c_k X     [flags = 1]
  // out = c0 X + L b8_1 - b2
  // step k gathers m8[(k+1)&1], writes fp16 bufs[k&1] and fp8 m8[k&1].
  clen_step<<<gS, B, 0, stream>>>(row_ptr, pk, m8[(M - 1) & 1], Xh, bufs[(M - 2) & 1],
                                  m8[(M - 2) & 1], coeffs, M - 2, 4, M, n);
  clen_step<<<gS, B, 0, stream>>>(row_ptr, pk, m8[(M - 2) & 1], Xh, bufs[(M - 3) & 1],
                                  m8[(M - 3) & 1], coeffs, M - 3, 2, M, n);
  for (int k = M - 4; k >= 1; --k) {
    clen_step<<<gS, B, 0, stream>>>(row_ptr, pk, m8[(k + 1) & 1], Xh, bufs[k & 1],
                                    m8[k & 1], coeffs, k, 1, M, n);
  }
  clen_final<<<gS, B, 0, stream>>>(row_ptr, pk, m8[1], bufs[0], X, out, coeffs, n);
}

// Round 7
// 938.513 us; speedup vs baseline: 1.4259x; 1.4259x over previous
//
#include <hip/hip_runtime.h>
#include <hip/hip_fp16.h>

#define FD 128          // feature dim
#define WPB 4           // waves per block (block = 256 threads)
#define RPW 2           // rows per wave (half-wave per row)
// rows per block = WPB*RPW = 8
// NOTE: algebraic elimination of b_{M-1} assumes M >= 4 (here M = 30).
// fp16 recurrence state (error-critical -b_{k+2} path) + fp8 e4m3 mirror planes
// [N][128B] as the gather source (round-6 numerics, passed at absmax 0.5).
// Round-7 change: HALF-WAVE ROW PAIRING. Lanes 0-31 gather row A, 32-63 row B;
// 4 edge-slots per half per instruction; 4 pk loads + 4 gathers issued before
// any consume -> 32 lines in flight per wave (round-5's proven saturation
// shape) on HALF the line demand. Rounds 5+6 isolated the bottleneck to
// latency x concurrency, not bytes or lines.

// ---------------- CSR build ----------------

__global__ void zero_i32(int* __restrict__ p, int n) {
  int i = blockIdx.x * blockDim.x + threadIdx.x;
  if (i < n) p[i] = 0;
}

__global__ void hist_kernel(const int* __restrict__ rows, int* __restrict__ cnt, int nnz) {
  int i = blockIdx.x * blockDim.x + threadIdx.x;
  if (i < nnz) atomicAdd(&cnt[rows[i]], 1);
}

// coalesced 3-phase scan
__global__ void block_reduce(const int* __restrict__ cnt, int* __restrict__ bsum, int n) {
  __shared__ int sm[256];
  int i = blockIdx.x * 256 + threadIdx.x;
  sm[threadIdx.x] = (i < n) ? cnt[i] : 0;
  __syncthreads();
  for (int off = 128; off > 0; off >>= 1) {
    if (threadIdx.x < off) sm[threadIdx.x] += sm[threadIdx.x + off];
    __syncthreads();
  }
  if (threadIdx.x == 0) bsum[blockIdx.x] = sm[0];
}

__global__ void scan_bsum(const int* __restrict__ bsum, int* __restrict__ bpre, int nb) {
  __shared__ int sm[1024];
  const int tid = threadIdx.x;
  sm[tid] = (tid < nb) ? bsum[tid] : 0;
  __syncthreads();
  for (int off = 1; off < 1024; off <<= 1) {
    int t = (tid >= off) ? sm[tid - off] : 0;
    __syncthreads();
    sm[tid] += t;
    __syncthreads();
  }
  if (tid < nb) bpre[tid] = (tid == 0) ? 0 : sm[tid - 1];
}

__global__ void block_scan(const int* __restrict__ cnt, const int* __restrict__ bpre,
                           int* __restrict__ row_ptr, int n) {
  __shared__ int sm[256];
  const int tid = threadIdx.x;
  int i = blockIdx.x * 256 + tid;
  sm[tid] = (i < n) ? cnt[i] : 0;
  __syncthreads();
  for (int off = 1; off < 256; off <<= 1) {
    int t = (tid >= off) ? sm[tid - off] : 0;
    __syncthreads();
    sm[tid] += t;
    __syncthreads();
  }
  if (i < n) row_ptr[i + 1] = sm[tid] + bpre[blockIdx.x];
  if (i == 0) row_ptr[0] = 0;
}

__global__ void copy_i32(const int* __restrict__ src, int* __restrict__ dst, int n) {
  int i = blockIdx.x * blockDim.x + threadIdx.x;
  if (i < n) dst[i] = src[i];
}

// packed edge scatter: one 8B store per edge. Column stored PRE-SCALED to the
// fp8-plane byte offset (col * 128 = col << 7) so the gather address is one add.
__global__ void scatter_kernel(const int* __restrict__ rows, const int* __restrict__ cols,
                               const float* __restrict__ vals, int* __restrict__ fill,
                               int2* __restrict__ pk, int nnz) {
  int i = blockIdx.x * blockDim.x + threadIdx.x;
  if (i < nnz) {
    int r = rows[i];
    int pos = atomicAdd(&fill[r], 1);
    pk[pos] = make_int2(cols[i] << 7, __float_as_int(vals[i]));
  }
}

// f32 [N][128] -> fp16 Xh [N][128] + fp8 X8 mirror (uint = 4 fp8 per thread-item)
__global__ void f32_to_f16_f8(const float* __restrict__ src, __half* __restrict__ dst,
                              unsigned int* __restrict__ dst8, int n4) {
  int i = blockIdx.x * blockDim.x + threadIdx.x;
  if (i < n4) {
    float4 v = ((const float4*)src)[i];
    __half2* d = (__half2*)dst + 2 * (size_t)i;
    d[0] = __floats2half2_rn(v.x, v.y);
    d[1] = __floats2half2_rn(v.z, v.w);
    int w = 0;
    w = __builtin_amdgcn_cvt_pk_fp8_f32(v.x, v.y, w, false);
    w = __builtin_amdgcn_cvt_pk_fp8_f32(v.z, v.w, w, true);
    dst8[i] = (unsigned int)w;
  }
}

// ---------------- fp8 half-wave gather ----------------
// half = lane>>5 picks row A/B. sub4 = (lane>>3)&3 picks 1 of 4 edge slots of
// that row. fl = lane&7 picks a uint4 (16 fp8 features). One gather instruction
// covers (4 edges of A + 4 of B) x 128B = 1KB over 8 fully-used lines; the
// unrolled body keeps 4 such instructions (32 lines) in flight per wave.

typedef float v2f __attribute__((ext_vector_type(2)));

__device__ __forceinline__ void consume16(uint4 raw, float v, float acc[16]) {
  v2f f;
  f = __builtin_amdgcn_cvt_pk_f32_fp8((int)raw.x, false);
  acc[0] = fmaf(v, f.x, acc[0]);  acc[1] = fmaf(v, f.y, acc[1]);
  f = __builtin_amdgcn_cvt_pk_f32_fp8((int)raw.x, true);
  acc[2] = fmaf(v, f.x, acc[2]);  acc[3] = fmaf(v, f.y, acc[3]);
  f = __builtin_amdgcn_cvt_pk_f32_fp8((int)raw.y, false);
  acc[4] = fmaf(v, f.x, acc[4]);  acc[5] = fmaf(v, f.y, acc[5]);
  f = __builtin_amdgcn_cvt_pk_f32_fp8((int)raw.y, true);
  acc[6] = fmaf(v, f.x, acc[6]);  acc[7] = fmaf(v, f.y, acc[7]);
  f = __builtin_amdgcn_cvt_pk_f32_fp8((int)raw.z, false);
  acc[8] = fmaf(v, f.x, acc[8]);  acc[9] = fmaf(v, f.y, acc[9]);
  f = __builtin_amdgcn_cvt_pk_f32_fp8((int)raw.z, true);
  acc[10] = fmaf(v, f.x, acc[10]); acc[11] = fmaf(v, f.y, acc[11]);
  f = __builtin_amdgcn_cvt_pk_f32_fp8((int)raw.w, false);
  acc[12] = fmaf(v, f.x, acc[12]); acc[13] = fmaf(v, f.y, acc[13]);
  f = __builtin_amdgcn_cvt_pk_f32_fp8((int)raw.w, true);
  acc[14] = fmaf(v, f.x, acc[14]); acc[15] = fmaf(v, f.y, acc[15]);
}

// Per-half cursor gather: processes up to 16 edges of this half's row per
// iteration; done halves spin on clamped (cached) re-reads with v=0 until the
// wave-wide condition clears. 4 pk loads, then 4 gathers, then 4 consumes.
__device__ __forceinline__ void gather_rows(const int2* __restrict__ pk,
                                            const char* __restrict__ Tfl,
                                            int e, int end, int sub4,
                                            float acc[16]) {
  while (__any(e < end)) {
    const int el = max(end - 1, 0);
    const int i0 = e + sub4, i1 = e + 4 + sub4, i2 = e + 8 + sub4, i3 = e + 12 + sub4;
    int2 cv0 = pk[min(i0, el)];
    int2 cv1 = pk[min(i1, el)];
    int2 cv2 = pk[min(i2, el)];
    int2 cv3 = pk[min(i3, el)];
    uint4 w0 = *(const uint4*)(Tfl + cv0.x);
    uint4 w1 = *(const uint4*)(Tfl + cv1.x);
    uint4 w2 = *(const uint4*)(Tfl + cv2.x);
    uint4 w3 = *(const uint4*)(Tfl + cv3.x);
    float v0 = (i0 < end) ? __int_as_float(cv0.y) : 0.f;
    float v1 = (i1 < end) ? __int_as_float(cv1.y) : 0.f;
    float v2 = (i2 < end) ? __int_as_float(cv2.y) : 0.f;
    float v3 = (i3 < end) ? __int_as_float(cv3.y) : 0.f;
    consume16(w0, v0, acc);
    consume16(w1, v1, acc);
    consume16(w2, v2, acc);
    consume16(w3, v3, acc);
    e += 16;
  }
}

// reduce over the 4 edge slots WITHIN each 32-lane half (xor 8, 16)
__device__ __forceinline__ void reduce_subs(float acc[16]) {
#pragma unroll
  for (int j = 0; j < 16; ++j) {
    acc[j] += __shfl_xor(acc[j], 8, 64);
    acc[j] += __shfl_xor(acc[j], 16, 64);
  }
}

// ---------------- Clenshaw steps ----------------
// b_k = g2*(L @ src8) - p + ck_eff * X   (fp16 state + fp8 gather mirror, fp32 math)
// flags: bit0 = read p from pd; bit1 = ck_eff = c_k - c_{M-1} (folds b_{M-1});
//        bit2 = g2 = 2*c_{M-1} (src8 is X8 standing in for b_{M-1} = c_{M-1} X).
// pd holds b_{k+2} (fp16) and receives b_k in place; dst8 receives the fp8 mirror.

__global__ __launch_bounds__(256) void clen_step(
    const int* __restrict__ rp, const int2* __restrict__ pk,
    const unsigned char* __restrict__ src8, const __half* __restrict__ Xh, __half* pd,
    unsigned char* __restrict__ dst8,
    const float* __restrict__ coeffs, int k, int flags, int M, int n) {
  const int lane = threadIdx.x & 63;
  const int halfw = lane >> 5;
  const int sub4 = (lane >> 3) & 3;
  const int fl = lane & 7;
  const int wid = threadIdx.x >> 6;
  const int wbase = blockIdx.x * (WPB * RPW) + wid * RPW;
  if (wbase >= n) return;
  const int r = wbase + halfw;
  const bool rok = (r < n);
  const int rv = rok ? r : (n - 1);

  int e = rp[rv];
  int end = rok ? rp[rv + 1] : e;
  const char* Tfl = (const char*)src8 + fl * 16;

  float acc[16];
#pragma unroll
  for (int j = 0; j < 16; ++j) acc[j] = 0.f;
  gather_rows(pk, Tfl, e, end, sub4, acc);
  reduce_subs(acc);

  if (sub4 == 0 && rok) {
    float ck = coeffs[k];
    if (flags & 2) ck -= coeffs[M - 1];
    const float g2 = (flags & 4) ? 2.f * coeffs[M - 1] : 2.f;
    const uint4* Xr = (const uint4*)(Xh + (size_t)r * FD);
    uint4 xr0 = Xr[fl * 2], xr1 = Xr[fl * 2 + 1];
    uint4 pr0 = make_uint4(0,0,0,0), pr1 = make_uint4(0,0,0,0);
    if (flags & 1) {
      const uint4* Pr = (const uint4*)(pd + (size_t)r * FD);
      pr0 = Pr[fl * 2]; pr1 = Pr[fl * 2 + 1];
    }
    const __half2* xh0 = (const __half2*)&xr0;
    const __half2* xh1 = (const __half2*)&xr1;
    const __half2* ph0 = (const __half2*)&pr0;
    const __half2* ph1 = (const __half2*)&pr1;
    float t[16];
#pragma unroll
    for (int q = 0; q < 4; ++q) {
      float2 x = __half22float2(xh0[q]);
      float2 p = (flags & 1) ? __half22float2(ph0[q]) : make_float2(0.f, 0.f);
      t[2*q]   = fmaf(g2, acc[2*q],   fmaf(ck, x.x, -p.x));
      t[2*q+1] = fmaf(g2, acc[2*q+1], fmaf(ck, x.y, -p.y));
    }
#pragma unroll
    for (int q = 0; q < 4; ++q) {
      float2 x = __half22float2(xh1[q]);
      float2 p = (flags & 1) ? __half22float2(ph1[q]) : make_float2(0.f, 0.f);
      t[8+2*q]   = fmaf(g2, acc[8+2*q],   fmaf(ck, x.x, -p.x));
      t[8+2*q+1] = fmaf(g2, acc[8+2*q+1], fmaf(ck, x.y, -p.y));
    }
    uint4 o0, o1;
    __half2* oh0 = (__half2*)&o0;
    __half2* oh1 = (__half2*)&o1;
#pragma unroll
    for (int q = 0; q < 4; ++q) {
      oh0[q] = __floats2half2_rn(t[2*q], t[2*q+1]);
      oh1[q] = __floats2half2_rn(t[8+2*q], t[8+2*q+1]);
    }
    ((uint4*)(pd + (size_t)r * FD))[fl * 2] = o0;
    ((uint4*)(pd + (size_t)r * FD))[fl * 2 + 1] = o1;
    uint4 m8;
    int w;
    w = 0;
    w = __builtin_amdgcn_cvt_pk_fp8_f32(t[0], t[1], w, false);
    w = __builtin_amdgcn_cvt_pk_fp8_f32(t[2], t[3], w, true);
    m8.x = (unsigned int)w;
    w = 0;
    w = __builtin_amdgcn_cvt_pk_fp8_f32(t[4], t[5], w, false);
    w = __builtin_amdgcn_cvt_pk_fp8_f32(t[6], t[7], w, true);
    m8.y = (unsigned int)w;
    w = 0;
    w = __builtin_amdgcn_cvt_pk_fp8_f32(t[8], t[9], w, false);
    w = __builtin_amdgcn_cvt_pk_fp8_f32(t[10], t[11], w, true);
    m8.z = (unsigned int)w;
    w = 0;
    w = __builtin_amdgcn_cvt_pk_fp8_f32(t[12], t[13], w, false);
    w = __builtin_amdgcn_cvt_pk_fp8_f32(t[14], t[15], w, true);
    m8.w = (unsigned int)w;
    ((uint4*)(dst8 + (size_t)r * FD))[fl] = m8;
  }
}

// out = c0*X + L @ b1 - b2   (fp32 X and output; b1 gathered from fp8 mirror)
__global__ __launch_bounds__(256) void clen_final(
    const int* __restrict__ rp, const int2* __restrict__ pk,
    const unsigned char* __restrict__ b18, const __half* __restrict__ b2,
    const float* __restrict__ X, float* __restrict__ out,
    const float* __restrict__ coeffs, int n) {
  const int lane = threadIdx.x & 63;
  const int halfw = lane >> 5;
  const int sub4 = (lane >> 3) & 3;
  const int fl = lane & 7;
  const int wid = threadIdx.x >> 6;
  const int wbase = blockIdx.x * (WPB * RPW) + wid * RPW;
  if (wbase >= n) return;
  const int r = wbase + halfw;
  const bool rok = (r < n);
  const int rv = rok ? r : (n - 1);

  int e = rp[rv];
  int end = rok ? rp[rv + 1] : e;
  const char* Tfl = (const char*)b18 + fl * 16;

  float acc[16];
#pragma unroll
  for (int j = 0; j < 16; ++j) acc[j] = 0.f;
  gather_rows(pk, Tfl, e, end, sub4, acc);
  reduce_subs(acc);

  if (sub4 == 0 && rok) {
    const float c0 = coeffs[0];
    const uint4* Br = (const uint4*)(b2 + (size_t)r * FD);
    uint4 pr0 = Br[fl * 2], pr1 = Br[fl * 2 + 1];
    const float4* Xr = (const float4*)(X + (size_t)r * FD);
    float4 x0 = Xr[fl * 4], x1 = Xr[fl * 4 + 1], x2 = Xr[fl * 4 + 2], x3 = Xr[fl * 4 + 3];
    const __half2* ph0 = (const __half2*)&pr0;
    const __half2* ph1 = (const __half2*)&pr1;
    float p[16];
#pragma unroll
    for (int q = 0; q < 4; ++q) {
      float2 a = __half22float2(ph0[q]);
      p[2*q] = a.x; p[2*q+1] = a.y;
      float2 b = __half22float2(ph1[q]);
      p[8+2*q] = b.x; p[8+2*q+1] = b.y;
    }
    float4 o0, o1, o2, o3;
    o0.x = fmaf(c0, x0.x, acc[0] - p[0]);
    o0.y = fmaf(c0, x0.y, acc[1] - p[1]);
    o0.z = fmaf(c0, x0.z, acc[2] - p[2]);
    o0.w = fmaf(c0, x0.w, acc[3] - p[3]);
    o1.x = fmaf(c0, x1.x, acc[4] - p[4]);
    o1.y = fmaf(c0, x1.y, acc[5] - p[5]);
    o1.z = fmaf(c0, x1.z, acc[6] - p[6]);
    o1.w = fmaf(c0, x1.w, acc[7] - p[7]);
    o2.x = fmaf(c0, x2.x, acc[8] - p[8]);
    o2.y = fmaf(c0, x2.y, acc[9] - p[9]);
    o2.z = fmaf(c0, x2.z, acc[10] - p[10]);
    o2.w = fmaf(c0, x2.w, acc[11] - p[11]);
    o3.x = fmaf(c0, x3.x, acc[12] - p[12]);
    o3.y = fmaf(c0, x3.y, acc[13] - p[13]);
    o3.z = fmaf(c0, x3.z, acc[14] - p[14]);
    o3.w = fmaf(c0, x3.w, acc[15] - p[15]);
    float4* Or = (float4*)(out + (size_t)r * FD);
    Or[fl * 4] = o0; Or[fl * 4 + 1] = o1; Or[fl * 4 + 2] = o2; Or[fl * 4 + 3] = o3;
  }
}

// ---------------- launch ----------------

extern "C" void kernel_launch(void* const* d_in, const int* in_sizes, int n_in,
                              void* d_out, int out_size, void* d_ws, size_t ws_size,
                              hipStream_t stream) {
  const int* rows = (const int*)d_in[0];
  const int* cols = (const int*)d_in[1];
  const float* vals = (const float*)d_in[2];
  const float* X = (const float*)d_in[3];
  const float* coeffs = (const float*)d_in[4];
  float* out = (float*)d_out;

  const int nnz = in_sizes[0];
  const int n = in_sizes[3] / FD;
  const int M = in_sizes[4];

  auto align_up = [](size_t x) { return (x + 255) & ~(size_t)255; };
  char* w = (char*)d_ws;
  size_t off = 0;
  int* row_ptr = (int*)(w + off); off = align_up(off + (size_t)(n + 1) * 4);
  int* row_fill = (int*)(w + off); off = align_up(off + (size_t)n * 4);
  int* bsum = (int*)(w + off); off = align_up(off + 1024 * 4);
  int* bpre = (int*)(w + off); off = align_up(off + 1024 * 4);
  int2* pk = (int2*)(w + off); off = align_up(off + (size_t)nnz * 8);
  __half* Xh = (__half*)(w + off); off = align_up(off + (size_t)n * FD * 2);
  __half* buf0 = (__half*)(w + off); off = align_up(off + (size_t)n * FD * 2);
  __half* buf1 = (__half*)(w + off); off = align_up(off + (size_t)n * FD * 2);
  unsigned char* m80 = (unsigned char*)(w + off); off = align_up(off + (size_t)n * FD);
  unsigned char* m81 = (unsigned char*)(w + off); off = align_up(off + (size_t)n * FD);
  __half* bufs[2] = {buf0, buf1};
  unsigned char* m8[2] = {m80, m81};
  (void)ws_size;

  const int B = 256;
  const int gN = (n + B - 1) / B;
  const int gE = (nnz + B - 1) / B;
  const int gS = (n + WPB * RPW - 1) / (WPB * RPW);
  const int n4 = n * FD / 4;
  const int gC = (n4 + B - 1) / B;

  // CSR build
  zero_i32<<<gN, B, 0, stream>>>(row_fill, n);
  hist_kernel<<<gE, B, 0, stream>>>(rows, row_fill, nnz);
  block_reduce<<<gN, B, 0, stream>>>(row_fill, bsum, n);
  scan_bsum<<<1, 1024, 0, stream>>>(bsum, bpre, gN);
  block_scan<<<gN, B, 0, stream>>>(row_fill, bpre, row_ptr, n);
  copy_i32<<<gN, B, 0, stream>>>(row_ptr, row_fill, n);
  scatter_kernel<<<gE, B, 0, stream>>>(rows, cols, vals, row_fill, pk, nnz);
  // X -> fp16 Xh + fp8 X8; X8 lives in m8[(M-1)&1] (the plane step M-2 gathers,
  // first overwritten only at step M-3, after X8 is done serving).
  f32_to_f16_f8<<<gC, B, 0, stream>>>(X, Xh, (unsigned int*)m8[(M - 1) & 1], n4);

  // Clenshaw (b_{M-1} = c_{M-1} X eliminated algebraically; M >= 4):
  // k = M-2: b = 2 c_{M-1} (L X8) + c_{M-2} X            [flags = 4]
  // k = M-3: b = 2 (L b8_{M-2}) + (c_{M-3} - c_{M-1}) X  [flags = 2]
  // k = M-4..1: b = 2 (L b8_{k+1}) - b_{k+2} + c_k X     [flags = 1]
  // out = c0 X + L b8_1 - b2
  // step k gathers m8[(k+1)&1], writes fp16 bufs[k&1] and fp8 m8[k&1].
  clen_step<<<gS, B, 0, stream>>>(row_ptr, pk, m8[(M - 1) & 1], Xh, bufs[(M - 2) & 1],
                                  m8[(M - 2) & 1], coeffs, M - 2, 4, M, n);
  clen_step<<<gS, B, 0, stream>>>(row_ptr, pk, m8[(M - 2) & 1], Xh, bufs[(M - 3) & 1],
                                  m8[(M - 3) & 1], coeffs, M - 3, 2, M, n);
  for (int k = M - 4; k >= 1; --k) {
    clen_step<<<gS, B, 0, stream>>>(row_ptr, pk, m8[(k + 1) & 1], Xh, bufs[k & 1],
                                    m8[k & 1], coeffs, k, 1, M, n);
  }
  clen_final<<<gS, B, 0, stream>>>(row_ptr, pk, m8[1], bufs[0], X, out, coeffs, n);
}